// Round 7
// baseline (469.517 us; speedup 1.0000x reference)
//
#include <hip/hip_runtime.h>
#include <hip/hip_bf16.h>

#define NS 16384   // batch
#define H 256      // hidden
#define TH 768     // 3H
#define PRED 24    // decode steps
#define LDA 272    // LDS h-tile row stride (shorts); R3-R6-verified
#define WS_NEEDED (425984)

typedef short bf16x8 __attribute__((ext_vector_type(8)));
typedef float floatx4 __attribute__((ext_vector_type(4)));

__device__ __forceinline__ float b2f(unsigned short u) {
    return __uint_as_float(((unsigned int)u) << 16);
}
__device__ __forceinline__ unsigned short f2b(float f) {   // RTN-even bf16
    unsigned int u = __float_as_uint(f);
    return (unsigned short)((u + 0x7FFFu + ((u >> 16) & 1u)) >> 16);
}
__device__ __forceinline__ float fsig(float v) {
    return __builtin_amdgcn_rcpf(1.0f + __expf(-v));
}
__device__ __forceinline__ float ftanh(float v) {
    return 1.0f - 2.0f * __builtin_amdgcn_rcpf(1.0f + __expf(2.0f * v));
}

// ================= prep 1: rank-1 input-proj collapse + small vectors =================
__global__ void prep_proj(const void* __restrict__ WihP, const void* __restrict__ wprojP,
                          const void* __restrict__ bprojP, const void* __restrict__ bihP,
                          const void* __restrict__ bhhP, const void* __restrict__ woutP,
                          const void* __restrict__ boutP,
                          float* __restrict__ u, float* __restrict__ c,
                          float* __restrict__ bhn, float* __restrict__ wo,
                          float* __restrict__ b0) {
    const int j = blockIdx.x;        // 768
    const int lane = threadIdx.x;    // 64
    unsigned long long bm = __ballot(!(fabsf(b2f(((const unsigned short*)WihP)[lane])) <= 0.25f));
    const bool f32in = (bm != 0ull);

    float su = 0.f, sc = 0.f;
    if (f32in) {
        const float* row = (const float*)WihP + (size_t)j * H;
        const float* wp = (const float*)wprojP;
        const float* bp = (const float*)bprojP;
        for (int k = lane; k < H; k += 64) {
            float w = row[k];
            su = fmaf(w, wp[k], su); sc = fmaf(w, bp[k], sc);
        }
    } else {
        const unsigned short* row = (const unsigned short*)WihP + (size_t)j * H;
        const unsigned short* wp = (const unsigned short*)wprojP;
        const unsigned short* bp = (const unsigned short*)bprojP;
        for (int k = lane; k < H; k += 64) {
            float w = b2f(row[k]);
            su = fmaf(w, b2f(wp[k]), su); sc = fmaf(w, b2f(bp[k]), sc);
        }
    }
    for (int m = 32; m; m >>= 1) { su += __shfl_xor(su, m, 64); sc += __shfl_xor(sc, m, 64); }

    if (lane == 0) {
        float bih = f32in ? ((const float*)bihP)[j] : b2f(((const unsigned short*)bihP)[j]);
        float bhh = f32in ? ((const float*)bhhP)[j] : b2f(((const unsigned short*)bhhP)[j]);
        u[j] = su;
        c[j] = sc + bih + (j < 512 ? bhh : 0.f);
        if (j >= 512) bhn[j - 512] = bhh;
    }
    if (j < H && lane == 1)
        wo[j] = f32in ? ((const float*)woutP)[j] : b2f(((const unsigned short*)woutP)[j]);
    if (j == 0 && lane == 2)
        b0[0] = f32in ? ((const float*)boutP)[0] : b2f(((const unsigned short*)boutP)[0]);
}

// ================= prep 2: swizzle W_hh into MFMA-fragment-contiguous bf16 =================
// frag fi = (w*8 + kk)*3 + g ; within frag: lane*8 elems (R4-verified).
__global__ void prep_swz(const void* __restrict__ WhhP, unsigned short* __restrict__ Wp) {
    const int cidx = blockIdx.x * 256 + threadIdx.x;
    unsigned long long bm = __ballot(!(fabsf(b2f(((const unsigned short*)WhhP)[threadIdx.x & 63])) <= 0.25f));
    const bool f32in = (bm != 0ull);

    const int lane = cidx & 63;
    const int fi   = cidx >> 6;
    const int g    = fi % 3;
    const int kk   = (fi / 3) & 7;
    const int w    = fi / 24;
    const size_t src = (size_t)(g * 256 + w * 16 + (lane & 15)) * H + kk * 32 + (lane >> 4) * 8;
    unsigned short* dst = Wp + (size_t)cidx * 8;
    if (f32in) {
        const float* s = (const float*)WhhP + src;
#pragma unroll
        for (int e = 0; e < 8; ++e) dst[e] = f2b(s[e]);
    } else {
        const unsigned short* s = (const unsigned short*)WhhP + src;
#pragma unroll
        for (int e = 0; e < 8; ++e) dst[e] = s[e];
    }
}

// ================= fused 24-step decode: global->VGPR B with cyclic 2-ahead prefetch =====
// 256 blocks x 1024 thr (16 waves). Wave w owns h-cols [16w,16w+16); acc = 48 regs.
// B frags: coalesced 1KB global loads, rotating 3-buffer, prefetch wraps across steps
// (W is t-invariant). No barrier inside the K-loop -> loads stay in flight (vmcnt>0).
// h_old re-read from As (bf16) to stay under the 128-reg/wave budget (R5 spill lesson).
__global__ __launch_bounds__(1024)
void decode_swz(const void* __restrict__ encP, const void* __restrict__ WihP,
                const unsigned short* __restrict__ Wp,
                const float* __restrict__ u, const float* __restrict__ c,
                const float* __restrict__ bhnA, const float* __restrict__ woA,
                const float* __restrict__ b0A, void* __restrict__ outP) {
    __shared__ __align__(16) unsigned short As[64 * LDA];   // 34.8 KB bf16 h tile
    __shared__ float pred_part[16][64];                     // 4 KB
    __shared__ float pred_fin[64];
    __shared__ float pred_out[64][PRED];                    // 6 KB
    __shared__ int sflag;

    const int tid  = threadIdx.x;
    const int w    = tid >> 6;
    const int lane = tid & 63;
    const int lo   = lane & 15;
    const int quad = lane >> 4;
    const int m0   = blockIdx.x * 64;

    if (tid == 0) sflag = 0;
    __syncthreads();
    if (!(fabsf(b2f(((const unsigned short*)WihP)[tid])) <= 0.25f)) sflag = 1;
    __syncthreads();
    const bool f32in = (sflag != 0);

    const float*          encF = (const float*)encP;
    const unsigned short* encB = (const unsigned short*)encP;

    // stage h0 tile (bf16)
    for (int i = tid; i < 64 * H; i += 1024) {
        int r = i >> 8, col = i & 255;
        float hv = f32in ? encF[(size_t)(m0 + r) * H + col] : b2f(encB[(size_t)(m0 + r) * H + col]);
        As[r * LDA + col] = f2b(hv);
    }
    if (tid < 64) pred_fin[tid] = 0.f;   // start token x=0

    const int jj = w * 16 + lo;
    const float ur = u[jj], uz = u[256 + jj], un = u[512 + jj];
    const float cr = c[jj], cz = c[256 + jj], cn = c[512 + jj];
    const float bh = bhnA[jj], wov = woA[jj];
    const float b0 = b0A[0];

    const unsigned short* wp = Wp + (size_t)w * 12288 + lane * 8;  // + (kk*3+g)*512

    // preload chunks 0,1 (overlaps the As staging above)
    bf16x8 bA[3], bB[3], bC[3];
#pragma unroll
    for (int g = 0; g < 3; ++g) bA[g] = *(const bf16x8*)(wp + (0 * 3 + g) * 512);
#pragma unroll
    for (int g = 0; g < 3; ++g) bB[g] = *(const bf16x8*)(wp + (1 * 3 + g) * 512);

    __syncthreads();

#pragma unroll 1
    for (int t = 0; t < PRED; ++t) {
        floatx4 acc[3][4];
#pragma unroll
        for (int g = 0; g < 3; ++g)
#pragma unroll
            for (int im = 0; im < 4; ++im) acc[g][im] = (floatx4){0.f, 0.f, 0.f, 0.f};

        // ---- K-loop: barrier-free, 2-chunk-ahead cyclic prefetch ----
#pragma unroll
        for (int kk = 0; kk < 8; ++kk) {
            const int pk = (kk + 2) & 7;   // wraps to next step's chunks at kk=6,7
#pragma unroll
            for (int g = 0; g < 3; ++g)
                bC[g] = *(const bf16x8*)(wp + (pk * 3 + g) * 512);

            bf16x8 a[4];
#pragma unroll
            for (int im = 0; im < 4; ++im)
                a[im] = *(const bf16x8*)&As[(im * 16 + lo) * LDA + kk * 32 + quad * 8];
#pragma unroll
            for (int g = 0; g < 3; ++g)
#pragma unroll
                for (int im = 0; im < 4; ++im)
                    acc[g][im] = __builtin_amdgcn_mfma_f32_16x16x32_bf16(a[im], bA[g], acc[g][im], 0, 0, 0);
            // rotate buffers (free under full unroll)
#pragma unroll
            for (int g = 0; g < 3; ++g) { bA[g] = bB[g]; bB[g] = bC[g]; }
        }
        __syncthreads();   // all waves done reading As(t)

        // ---- epilogue: gates + h update + pred partials ----
#pragma unroll
        for (int im = 0; im < 4; ++im) {
#pragma unroll
            for (int v = 0; v < 4; ++v) {
                const int row = im * 16 + quad * 4 + v;
                const int hofs = row * LDA + jj;
                const float xv = pred_fin[row];
                const float hold = b2f(As[hofs]);       // h_old (bf16, reg-budget trade)
                float r  = fsig(fmaf(xv, ur, cr) + acc[0][im][v]);
                float z  = fsig(fmaf(xv, uz, cz) + acc[1][im][v]);
                float n  = ftanh(fmaf(xv, un, cn) + r * (acc[2][im][v] + bh));
                float hn = fmaf(z, hold - n, n);        // (1-z)*n + z*h
                As[hofs] = f2b(hn);
                float pv = hn * wov;
                pv += __shfl_xor(pv, 1, 64);
                pv += __shfl_xor(pv, 2, 64);
                pv += __shfl_xor(pv, 4, 64);
                pv += __shfl_xor(pv, 8, 64);
                if (lo == 0) pred_part[w][row] = pv;
            }
        }
        __syncthreads();   // As(t+1) + partials visible

        // ---- finalize: pred -> feedback + buffered output ----
        if (tid < 64) {
            float pr = b0;
#pragma unroll
            for (int ww = 0; ww < 16; ++ww) pr += pred_part[ww][tid];
            pred_fin[tid] = pr;
            pred_out[tid][t] = pr;
        }
        // next iteration's K-loop closing barrier orders pred_fin/pred_part reuse
    }
    __syncthreads();

    // single coalesced output store
    for (int i = tid; i < 64 * PRED; i += 1024) {
        int row = i / PRED, tt = i % PRED;
        float pr = pred_out[row][tt];
        if (f32in) ((float*)outP)[(size_t)(m0 + row) * PRED + tt] = pr;
        else ((unsigned short*)outP)[(size_t)(m0 + row) * PRED + tt] = f2b(pr);
    }
}

// ================= fallback (R3, proven): zero-workspace fused decode =================
__global__ __launch_bounds__(512, 2)
void decode_all(const void* __restrict__ encP,   const void* __restrict__ wprojP,
                const void* __restrict__ bprojP, const void* __restrict__ WihP,
                const void* __restrict__ bihP,   const void* __restrict__ WhhP,
                const void* __restrict__ bhhP,   const void* __restrict__ woutP,
                const void* __restrict__ boutP,  void* __restrict__ outP) {
    __shared__ __align__(16) unsigned short As[64 * LDA];
    __shared__ float u_lds[TH], c_lds[TH];
    __shared__ float bhn_lds[H], wo_lds[H];
    __shared__ float wp_lds[H], bp_lds[H];
    __shared__ float pred_lds[2][64];
    __shared__ int sflag;

    const int tid  = threadIdx.x;
    const int wid  = tid >> 6;
    const int lane = tid & 63;
    const int lo   = lane & 15;
    const int quad = lane >> 4;
    const int rh   = wid & 3;
    const int ch   = wid >> 2;
    const int m0   = blockIdx.x * 64;

    if (tid == 0) sflag = 0;
    __syncthreads();
    if (!(fabsf(b2f(((const unsigned short*)WihP)[tid])) <= 0.25f)) sflag = 1;
    __syncthreads();
    const bool f32in = (sflag != 0);

    const float*          encF = (const float*)encP;
    const unsigned short* encB = (const unsigned short*)encP;
    const unsigned short* WhhB = (const unsigned short*)WhhP;
    const float*          WhhF = (const float*)WhhP;

    if (tid < H) {
        wp_lds[tid] = f32in ? ((const float*)wprojP)[tid] : b2f(((const unsigned short*)wprojP)[tid]);
        bp_lds[tid] = f32in ? ((const float*)bprojP)[tid] : b2f(((const unsigned short*)bprojP)[tid]);
        wo_lds[tid] = f32in ? ((const float*)woutP)[tid]  : b2f(((const unsigned short*)woutP)[tid]);
    }
    __syncthreads();

    for (int j = tid; j < TH; j += 512) {
        float su = 0.f, sc = 0.f;
        if (f32in) {
            const float* row = (const float*)WihP + (size_t)j * H;
            for (int k = 0; k < H; ++k) { float w = row[k]; su = fmaf(w, wp_lds[k], su); sc = fmaf(w, bp_lds[k], sc); }
        } else {
            const unsigned short* row = (const unsigned short*)WihP + (size_t)j * H;
            for (int k = 0; k < H; ++k) { float w = b2f(row[k]); su = fmaf(w, wp_lds[k], su); sc = fmaf(w, bp_lds[k], sc); }
        }
        float bih = f32in ? ((const float*)bihP)[j] : b2f(((const unsigned short*)bihP)[j]);
        float bhh = f32in ? ((const float*)bhhP)[j] : b2f(((const unsigned short*)bhhP)[j]);
        u_lds[j] = su;
        c_lds[j] = sc + bih + (j < 512 ? bhh : 0.f);
        if (j >= 512) bhn_lds[j - 512] = bhh;
    }

    for (int i = tid; i < 64 * H; i += 512) {
        int r = i >> 8, col = i & 255;
        float hv = f32in ? encF[(size_t)(m0 + r) * H + col] : b2f(encB[(size_t)(m0 + r) * H + col]);
        As[r * LDA + col] = f2b(hv);
    }
    float hold[8][4];
#pragma unroll
    for (int s = 0; s < 8; ++s)
#pragma unroll
        for (int v = 0; v < 4; ++v) {
            int row = m0 + rh * 16 + quad * 4 + v;
            int jj  = ch * 128 + s * 16 + lo;
            hold[s][v] = f32in ? encF[(size_t)row * H + jj] : b2f(encB[(size_t)row * H + jj]);
        }
    const float b0 = f32in ? ((const float*)boutP)[0] : b2f(((const unsigned short*)boutP)[0]);

    float xm[4] = {0.f, 0.f, 0.f, 0.f};
    __syncthreads();

    const int aBase = (rh * 16 + lo) * LDA;
    const int wCol0 = ch * 128 + lo;

#pragma unroll 1
    for (int t = 0; t < PRED; ++t) {
        floatx4 acc[3][8];
#pragma unroll
        for (int g = 0; g < 3; ++g)
#pragma unroll
            for (int s = 0; s < 8; ++s) acc[g][s] = (floatx4){0.f, 0.f, 0.f, 0.f};

        if (f32in) {
#pragma unroll 1
            for (int kk = 0; kk < 8; ++kk) {
                bf16x8 a = *(const bf16x8*)&As[aBase + kk * 32 + quad * 8];
#pragma unroll
                for (int g = 0; g < 3; ++g)
#pragma unroll
                    for (int s = 0; s < 8; ++s) {
                        const float* wr = WhhF + (size_t)(g * 256 + wCol0 + s * 16) * H + kk * 32 + quad * 8;
                        float4 w0 = *(const float4*)wr;
                        float4 w1 = *(const float4*)(wr + 4);
                        bf16x8 b;
                        b[0] = (short)f2b(w0.x); b[1] = (short)f2b(w0.y);
                        b[2] = (short)f2b(w0.z); b[3] = (short)f2b(w0.w);
                        b[4] = (short)f2b(w1.x); b[5] = (short)f2b(w1.y);
                        b[6] = (short)f2b(w1.z); b[7] = (short)f2b(w1.w);
                        acc[g][s] = __builtin_amdgcn_mfma_f32_16x16x32_bf16(a, b, acc[g][s], 0, 0, 0);
                    }
            }
        } else {
#pragma unroll 1
            for (int kk = 0; kk < 8; ++kk) {
                bf16x8 a = *(const bf16x8*)&As[aBase + kk * 32 + quad * 8];
#pragma unroll
                for (int g = 0; g < 3; ++g)
#pragma unroll
                    for (int s = 0; s < 8; ++s) {
                        bf16x8 b = *(const bf16x8*)(WhhB + (size_t)(g * 256 + wCol0 + s * 16) * H + kk * 32 + quad * 8);
                        acc[g][s] = __builtin_amdgcn_mfma_f32_16x16x32_bf16(a, b, acc[g][s], 0, 0, 0);
                    }
            }
        }
        __syncthreads();

        float p[4] = {0.f, 0.f, 0.f, 0.f};
#pragma unroll
        for (int s = 0; s < 8; ++s) {
            const int jj = ch * 128 + s * 16 + lo;
            const float urr = u_lds[jj], uzz = u_lds[256 + jj], unn = u_lds[512 + jj];
            const float crr = c_lds[jj], czz = c_lds[256 + jj], cnn = c_lds[512 + jj];
            const float bhn = bhn_lds[jj], wov = wo_lds[jj];
#pragma unroll
            for (int v = 0; v < 4; ++v) {
                const float xv = xm[v];
                float r  = fsig(fmaf(xv, urr, crr) + acc[0][s][v]);
                float z  = fsig(fmaf(xv, uzz, czz) + acc[1][s][v]);
                float n  = ftanh(fmaf(xv, unn, cnn) + r * (acc[2][s][v] + bhn));
                float hn = fmaf(z, hold[s][v] - n, n);
                hold[s][v] = hn;
                As[(rh * 16 + quad * 4 + v) * LDA + jj] = f2b(hn);
                p[v] = fmaf(hn, wov, p[v]);
            }
        }
#pragma unroll
        for (int v = 0; v < 4; ++v) {
            float pv = p[v];
            pv += __shfl_xor(pv, 1, 64);
            pv += __shfl_xor(pv, 2, 64);
            pv += __shfl_xor(pv, 4, 64);
            pv += __shfl_xor(pv, 8, 64);
            if (lo == 0) pred_lds[ch][rh * 16 + quad * 4 + v] = pv;
        }
        __syncthreads();

#pragma unroll
        for (int v = 0; v < 4; ++v) {
            const int ml = rh * 16 + quad * 4 + v;
            xm[v] = b0 + pred_lds[0][ml] + pred_lds[1][ml];
        }
        if (tid < 64) {
            float pr = b0 + pred_lds[0][tid] + pred_lds[1][tid];
            if (f32in) ((float*)outP)[(size_t)(m0 + tid) * PRED + t] = pr;
            else ((unsigned short*)outP)[(size_t)(m0 + tid) * PRED + t] = f2b(pr);
        }
    }
}

extern "C" void kernel_launch(void* const* d_in, const int* in_sizes, int n_in,
                              void* d_out, int out_size, void* d_ws, size_t ws_size,
                              hipStream_t stream) {
    if (ws_size >= (size_t)WS_NEEDED) {
        char* ws = (char*)d_ws;
        unsigned short* Wp = (unsigned short*)ws;          // 393216 B
        float* u   = (float*)(ws + 393216);
        float* c   = (float*)(ws + 396288);
        float* bhn = (float*)(ws + 399360);
        float* wo  = (float*)(ws + 400384);
        float* b0  = (float*)(ws + 401408);
        prep_proj<<<TH, 64, 0, stream>>>(d_in[3], d_in[1], d_in[2], d_in[4], d_in[6],
                                         d_in[7], d_in[8], u, c, bhn, wo, b0);
        prep_swz<<<96, 256, 0, stream>>>(d_in[5], Wp);
        decode_swz<<<NS / 64, 1024, 0, stream>>>(d_in[0], d_in[3], Wp, u, c, bhn, wo, b0, d_out);
    } else {
        decode_all<<<NS / 64, 512, 0, stream>>>(d_in[0], d_in[1], d_in[2], d_in[3],
                                                d_in[4], d_in[5], d_in[6], d_in[7],
                                                d_in[8], d_out);
    }
}

// Round 8
// 440.882 us; speedup vs baseline: 1.0650x; 1.0650x over previous
//
#include <hip/hip_runtime.h>
#include <hip/hip_bf16.h>

#define NS 16384   // batch
#define H 256      // hidden
#define TH 768     // 3H
#define PRED 24    // decode steps
#define LDA 272    // LDS h-tile row stride (shorts); R3-R7-verified
#define WS_NEEDED (425984)

typedef short bf16x8 __attribute__((ext_vector_type(8)));
typedef float floatx4 __attribute__((ext_vector_type(4)));

// LDS-only barrier: orders ds_read/ds_write across the workgroup WITHOUT
// draining vmcnt -> global-load prefetch pipeline survives the barrier.
// (__syncthreads() compiles to s_waitcnt vmcnt(0) lgkmcnt(0); s_barrier,
// which killed the W prefetch twice per step in R4-R7.)
#define BAR_LDS() asm volatile("s_waitcnt lgkmcnt(0)\n\ts_barrier" ::: "memory")

__device__ __forceinline__ float b2f(unsigned short u) {
    return __uint_as_float(((unsigned int)u) << 16);
}
__device__ __forceinline__ unsigned short f2b(float f) {   // RTN-even bf16
    unsigned int u = __float_as_uint(f);
    return (unsigned short)((u + 0x7FFFu + ((u >> 16) & 1u)) >> 16);
}
__device__ __forceinline__ float fsig(float v) {
    return __builtin_amdgcn_rcpf(1.0f + __expf(-v));
}
__device__ __forceinline__ float ftanh(float v) {
    return 1.0f - 2.0f * __builtin_amdgcn_rcpf(1.0f + __expf(2.0f * v));
}

// ================= prep 1: rank-1 input-proj collapse + small vectors =================
__global__ void prep_proj(const void* __restrict__ WihP, const void* __restrict__ wprojP,
                          const void* __restrict__ bprojP, const void* __restrict__ bihP,
                          const void* __restrict__ bhhP, const void* __restrict__ woutP,
                          const void* __restrict__ boutP,
                          float* __restrict__ u, float* __restrict__ c,
                          float* __restrict__ bhn, float* __restrict__ wo,
                          float* __restrict__ b0) {
    const int j = blockIdx.x;        // 768
    const int lane = threadIdx.x;    // 64
    unsigned long long bm = __ballot(!(fabsf(b2f(((const unsigned short*)WihP)[lane])) <= 0.25f));
    const bool f32in = (bm != 0ull);

    float su = 0.f, sc = 0.f;
    if (f32in) {
        const float* row = (const float*)WihP + (size_t)j * H;
        const float* wp = (const float*)wprojP;
        const float* bp = (const float*)bprojP;
        for (int k = lane; k < H; k += 64) {
            float w = row[k];
            su = fmaf(w, wp[k], su); sc = fmaf(w, bp[k], sc);
        }
    } else {
        const unsigned short* row = (const unsigned short*)WihP + (size_t)j * H;
        const unsigned short* wp = (const unsigned short*)wprojP;
        const unsigned short* bp = (const unsigned short*)bprojP;
        for (int k = lane; k < H; k += 64) {
            float w = b2f(row[k]);
            su = fmaf(w, b2f(wp[k]), su); sc = fmaf(w, b2f(bp[k]), sc);
        }
    }
    for (int m = 32; m; m >>= 1) { su += __shfl_xor(su, m, 64); sc += __shfl_xor(sc, m, 64); }

    if (lane == 0) {
        float bih = f32in ? ((const float*)bihP)[j] : b2f(((const unsigned short*)bihP)[j]);
        float bhh = f32in ? ((const float*)bhhP)[j] : b2f(((const unsigned short*)bhhP)[j]);
        u[j] = su;
        c[j] = sc + bih + (j < 512 ? bhh : 0.f);
        if (j >= 512) bhn[j - 512] = bhh;
    }
    if (j < H && lane == 1)
        wo[j] = f32in ? ((const float*)woutP)[j] : b2f(((const unsigned short*)woutP)[j]);
    if (j == 0 && lane == 2)
        b0[0] = f32in ? ((const float*)boutP)[0] : b2f(((const unsigned short*)boutP)[0]);
}

// ================= prep 2: swizzle W_hh into MFMA-fragment-contiguous bf16 =================
// frag fi = (w*8 + kk)*3 + g ; within frag: lane*8 elems (R4-verified).
__global__ void prep_swz(const void* __restrict__ WhhP, unsigned short* __restrict__ Wp) {
    const int cidx = blockIdx.x * 256 + threadIdx.x;
    unsigned long long bm = __ballot(!(fabsf(b2f(((const unsigned short*)WhhP)[threadIdx.x & 63])) <= 0.25f));
    const bool f32in = (bm != 0ull);

    const int lane = cidx & 63;
    const int fi   = cidx >> 6;
    const int g    = fi % 3;
    const int kk   = (fi / 3) & 7;
    const int w    = fi / 24;
    const size_t src = (size_t)(g * 256 + w * 16 + (lane & 15)) * H + kk * 32 + (lane >> 4) * 8;
    unsigned short* dst = Wp + (size_t)cidx * 8;
    if (f32in) {
        const float* s = (const float*)WhhP + src;
#pragma unroll
        for (int e = 0; e < 8; ++e) dst[e] = f2b(s[e]);
    } else {
        const unsigned short* s = (const unsigned short*)WhhP + src;
#pragma unroll
        for (int e = 0; e < 8; ++e) dst[e] = s[e];
    }
}

// ================= fused 24-step decode: non-draining barriers + continuous prefetch =====
// 256 blocks x 1024 thr (16 waves). Wave w owns h-cols [16w,16w+16); acc = 48 regs.
// B frags: coalesced 1KB global loads, rotating 3-buffer, 2 chunks ahead, wrapping
// across steps (W is t-invariant). In-loop barriers are LDS-only (no vmcnt drain),
// so the W pipeline runs continuously for all 24 steps (hipBLASLt pattern).
__global__ __launch_bounds__(1024)
void decode_swz(const void* __restrict__ encP, const void* __restrict__ WihP,
                const unsigned short* __restrict__ Wp,
                const float* __restrict__ u, const float* __restrict__ c,
                const float* __restrict__ bhnA, const float* __restrict__ woA,
                const float* __restrict__ b0A, void* __restrict__ outP) {
    __shared__ __align__(16) unsigned short As[64 * LDA];   // 34.8 KB bf16 h tile
    __shared__ float pred_part[16][64];                     // 4 KB
    __shared__ float pred_fin[64];
    __shared__ float pred_out[64][PRED];                    // 6 KB
    __shared__ int sflag;

    const int tid  = threadIdx.x;
    const int w    = tid >> 6;
    const int lane = tid & 63;
    const int lo   = lane & 15;
    const int quad = lane >> 4;
    const int m0   = blockIdx.x * 64;

    if (tid == 0) sflag = 0;
    __syncthreads();
    if (!(fabsf(b2f(((const unsigned short*)WihP)[tid])) <= 0.25f)) sflag = 1;
    __syncthreads();
    const bool f32in = (sflag != 0);

    const float*          encF = (const float*)encP;
    const unsigned short* encB = (const unsigned short*)encP;

    // stage h0 tile (bf16)
    for (int i = tid; i < 64 * H; i += 1024) {
        int r = i >> 8, col = i & 255;
        float hv = f32in ? encF[(size_t)(m0 + r) * H + col] : b2f(encB[(size_t)(m0 + r) * H + col]);
        As[r * LDA + col] = f2b(hv);
    }
    if (tid < 64) pred_fin[tid] = 0.f;   // start token x=0

    const int jj = w * 16 + lo;
    const float ur = u[jj], uz = u[256 + jj], un = u[512 + jj];
    const float cr = c[jj], cz = c[256 + jj], cn = c[512 + jj];
    const float bh = bhnA[jj], wov = woA[jj];
    const float b0 = b0A[0];

    const unsigned short* wp = Wp + (size_t)w * 12288 + lane * 8;  // + (kk*3+g)*512

    // preload chunks 0,1 (overlaps the As staging above)
    bf16x8 bA[3], bB[3], bC[3];
#pragma unroll
    for (int g = 0; g < 3; ++g) bA[g] = *(const bf16x8*)(wp + (0 * 3 + g) * 512);
#pragma unroll
    for (int g = 0; g < 3; ++g) bB[g] = *(const bf16x8*)(wp + (1 * 3 + g) * 512);

    __syncthreads();   // one-time full drain (staging); cost negligible

#pragma unroll 1
    for (int t = 0; t < PRED; ++t) {
        floatx4 acc[3][4];
#pragma unroll
        for (int g = 0; g < 3; ++g)
#pragma unroll
            for (int im = 0; im < 4; ++im) acc[g][im] = (floatx4){0.f, 0.f, 0.f, 0.f};

        // ---- K-loop: barrier-free inside, 2-chunk-ahead cyclic prefetch ----
#pragma unroll
        for (int kk = 0; kk < 8; ++kk) {
            const int pk = (kk + 2) & 7;   // wraps to next step's chunks at kk=6,7
#pragma unroll
            for (int g = 0; g < 3; ++g)
                bC[g] = *(const bf16x8*)(wp + (pk * 3 + g) * 512);

            bf16x8 a[4];
#pragma unroll
            for (int im = 0; im < 4; ++im)
                a[im] = *(const bf16x8*)&As[(im * 16 + lo) * LDA + kk * 32 + quad * 8];
#pragma unroll
            for (int g = 0; g < 3; ++g)
#pragma unroll
                for (int im = 0; im < 4; ++im)
                    acc[g][im] = __builtin_amdgcn_mfma_f32_16x16x32_bf16(a[im], bA[g], acc[g][im], 0, 0, 0);
            // rotate buffers (free under full unroll)
#pragma unroll
            for (int g = 0; g < 3; ++g) { bA[g] = bB[g]; bB[g] = bC[g]; }
        }
        BAR_LDS();   // all waves done reading As(t); W prefetch stays in flight

        // ---- epilogue: gates + h update + pred partials ----
#pragma unroll
        for (int im = 0; im < 4; ++im) {
#pragma unroll
            for (int v = 0; v < 4; ++v) {
                const int row = im * 16 + quad * 4 + v;
                const int hofs = row * LDA + jj;
                const float xv = pred_fin[row];
                const float hold = b2f(As[hofs]);       // h_old (bf16)
                float r  = fsig(fmaf(xv, ur, cr) + acc[0][im][v]);
                float z  = fsig(fmaf(xv, uz, cz) + acc[1][im][v]);
                float n  = ftanh(fmaf(xv, un, cn) + r * (acc[2][im][v] + bh));
                float hn = fmaf(z, hold - n, n);        // (1-z)*n + z*h
                As[hofs] = f2b(hn);
                float pv = hn * wov;
                pv += __shfl_xor(pv, 1, 64);
                pv += __shfl_xor(pv, 2, 64);
                pv += __shfl_xor(pv, 4, 64);
                pv += __shfl_xor(pv, 8, 64);
                if (lo == 0) pred_part[w][row] = pv;
            }
        }
        BAR_LDS();   // As(t+1) + partials visible; W prefetch still in flight

        // ---- finalize: pred -> feedback + buffered output (concurrent w/ next K-loop) ----
        if (tid < 64) {
            float pr = b0;
#pragma unroll
            for (int ww = 0; ww < 16; ++ww) pr += pred_part[ww][tid];
            pred_fin[tid] = pr;
            pred_out[tid][t] = pr;
        }
        // next iteration's first BAR_LDS orders pred_fin/pred_part reuse
    }
    __syncthreads();

    // single coalesced output store
    for (int i = tid; i < 64 * PRED; i += 1024) {
        int row = i / PRED, tt = i % PRED;
        float pr = pred_out[row][tt];
        if (f32in) ((float*)outP)[(size_t)(m0 + row) * PRED + tt] = pr;
        else ((unsigned short*)outP)[(size_t)(m0 + row) * PRED + tt] = f2b(pr);
    }
}

// ================= fallback (R3, proven): zero-workspace fused decode =================
__global__ __launch_bounds__(512, 2)
void decode_all(const void* __restrict__ encP,   const void* __restrict__ wprojP,
                const void* __restrict__ bprojP, const void* __restrict__ WihP,
                const void* __restrict__ bihP,   const void* __restrict__ WhhP,
                const void* __restrict__ bhhP,   const void* __restrict__ woutP,
                const void* __restrict__ boutP,  void* __restrict__ outP) {
    __shared__ __align__(16) unsigned short As[64 * LDA];
    __shared__ float u_lds[TH], c_lds[TH];
    __shared__ float bhn_lds[H], wo_lds[H];
    __shared__ float wp_lds[H], bp_lds[H];
    __shared__ float pred_lds[2][64];
    __shared__ int sflag;

    const int tid  = threadIdx.x;
    const int wid  = tid >> 6;
    const int lane = tid & 63;
    const int lo   = lane & 15;
    const int quad = lane >> 4;
    const int rh   = wid & 3;
    const int ch   = wid >> 2;
    const int m0   = blockIdx.x * 64;

    if (tid == 0) sflag = 0;
    __syncthreads();
    if (!(fabsf(b2f(((const unsigned short*)WihP)[tid])) <= 0.25f)) sflag = 1;
    __syncthreads();
    const bool f32in = (sflag != 0);

    const float*          encF = (const float*)encP;
    const unsigned short* encB = (const unsigned short*)encP;
    const unsigned short* WhhB = (const unsigned short*)WhhP;
    const float*          WhhF = (const float*)WhhP;

    if (tid < H) {
        wp_lds[tid] = f32in ? ((const float*)wprojP)[tid] : b2f(((const unsigned short*)wprojP)[tid]);
        bp_lds[tid] = f32in ? ((const float*)bprojP)[tid] : b2f(((const unsigned short*)bprojP)[tid]);
        wo_lds[tid] = f32in ? ((const float*)woutP)[tid]  : b2f(((const unsigned short*)woutP)[tid]);
    }
    __syncthreads();

    for (int j = tid; j < TH; j += 512) {
        float su = 0.f, sc = 0.f;
        if (f32in) {
            const float* row = (const float*)WihP + (size_t)j * H;
            for (int k = 0; k < H; ++k) { float w = row[k]; su = fmaf(w, wp_lds[k], su); sc = fmaf(w, bp_lds[k], sc); }
        } else {
            const unsigned short* row = (const unsigned short*)WihP + (size_t)j * H;
            for (int k = 0; k < H; ++k) { float w = b2f(row[k]); su = fmaf(w, wp_lds[k], su); sc = fmaf(w, bp_lds[k], sc); }
        }
        float bih = f32in ? ((const float*)bihP)[j] : b2f(((const unsigned short*)bihP)[j]);
        float bhh = f32in ? ((const float*)bhhP)[j] : b2f(((const unsigned short*)bhhP)[j]);
        u_lds[j] = su;
        c_lds[j] = sc + bih + (j < 512 ? bhh : 0.f);
        if (j >= 512) bhn_lds[j - 512] = bhh;
    }

    for (int i = tid; i < 64 * H; i += 512) {
        int r = i >> 8, col = i & 255;
        float hv = f32in ? encF[(size_t)(m0 + r) * H + col] : b2f(encB[(size_t)(m0 + r) * H + col]);
        As[r * LDA + col] = f2b(hv);
    }
    float hold[8][4];
#pragma unroll
    for (int s = 0; s < 8; ++s)
#pragma unroll
        for (int v = 0; v < 4; ++v) {
            int row = m0 + rh * 16 + quad * 4 + v;
            int jj  = ch * 128 + s * 16 + lo;
            hold[s][v] = f32in ? encF[(size_t)row * H + jj] : b2f(encB[(size_t)row * H + jj]);
        }
    const float b0 = f32in ? ((const float*)boutP)[0] : b2f(((const unsigned short*)boutP)[0]);

    float xm[4] = {0.f, 0.f, 0.f, 0.f};
    __syncthreads();

    const int aBase = (rh * 16 + lo) * LDA;
    const int wCol0 = ch * 128 + lo;

#pragma unroll 1
    for (int t = 0; t < PRED; ++t) {
        floatx4 acc[3][8];
#pragma unroll
        for (int g = 0; g < 3; ++g)
#pragma unroll
            for (int s = 0; s < 8; ++s) acc[g][s] = (floatx4){0.f, 0.f, 0.f, 0.f};

        if (f32in) {
#pragma unroll 1
            for (int kk = 0; kk < 8; ++kk) {
                bf16x8 a = *(const bf16x8*)&As[aBase + kk * 32 + quad * 8];
#pragma unroll
                for (int g = 0; g < 3; ++g)
#pragma unroll
                    for (int s = 0; s < 8; ++s) {
                        const float* wr = WhhF + (size_t)(g * 256 + wCol0 + s * 16) * H + kk * 32 + quad * 8;
                        float4 w0 = *(const float4*)wr;
                        float4 w1 = *(const float4*)(wr + 4);
                        bf16x8 b;
                        b[0] = (short)f2b(w0.x); b[1] = (short)f2b(w0.y);
                        b[2] = (short)f2b(w0.z); b[3] = (short)f2b(w0.w);
                        b[4] = (short)f2b(w1.x); b[5] = (short)f2b(w1.y);
                        b[6] = (short)f2b(w1.z); b[7] = (short)f2b(w1.w);
                        acc[g][s] = __builtin_amdgcn_mfma_f32_16x16x32_bf16(a, b, acc[g][s], 0, 0, 0);
                    }
            }
        } else {
#pragma unroll 1
            for (int kk = 0; kk < 8; ++kk) {
                bf16x8 a = *(const bf16x8*)&As[aBase + kk * 32 + quad * 8];
#pragma unroll
                for (int g = 0; g < 3; ++g)
#pragma unroll
                    for (int s = 0; s < 8; ++s) {
                        bf16x8 b = *(const bf16x8*)(WhhB + (size_t)(g * 256 + wCol0 + s * 16) * H + kk * 32 + quad * 8);
                        acc[g][s] = __builtin_amdgcn_mfma_f32_16x16x32_bf16(a, b, acc[g][s], 0, 0, 0);
                    }
            }
        }
        __syncthreads();

        float p[4] = {0.f, 0.f, 0.f, 0.f};
#pragma unroll
        for (int s = 0; s < 8; ++s) {
            const int jj = ch * 128 + s * 16 + lo;
            const float urr = u_lds[jj], uzz = u_lds[256 + jj], unn = u_lds[512 + jj];
            const float crr = c_lds[jj], czz = c_lds[256 + jj], cnn = c_lds[512 + jj];
            const float bhn = bhn_lds[jj], wov = wo_lds[jj];
#pragma unroll
            for (int v = 0; v < 4; ++v) {
                const float xv = xm[v];
                float r  = fsig(fmaf(xv, urr, crr) + acc[0][s][v]);
                float z  = fsig(fmaf(xv, uzz, czz) + acc[1][s][v]);
                float n  = ftanh(fmaf(xv, unn, cnn) + r * (acc[2][s][v] + bhn));
                float hn = fmaf(z, hold[s][v] - n, n);
                hold[s][v] = hn;
                As[(rh * 16 + quad * 4 + v) * LDA + jj] = f2b(hn);
                p[v] = fmaf(hn, wov, p[v]);
            }
        }
#pragma unroll
        for (int v = 0; v < 4; ++v) {
            float pv = p[v];
            pv += __shfl_xor(pv, 1, 64);
            pv += __shfl_xor(pv, 2, 64);
            pv += __shfl_xor(pv, 4, 64);
            pv += __shfl_xor(pv, 8, 64);
            if (lo == 0) pred_lds[ch][rh * 16 + quad * 4 + v] = pv;
        }
        __syncthreads();

#pragma unroll
        for (int v = 0; v < 4; ++v) {
            const int ml = rh * 16 + quad * 4 + v;
            xm[v] = b0 + pred_lds[0][ml] + pred_lds[1][ml];
        }
        if (tid < 64) {
            float pr = b0 + pred_lds[0][tid] + pred_lds[1][tid];
            if (f32in) ((float*)outP)[(size_t)(m0 + tid) * PRED + t] = pr;
            else ((unsigned short*)outP)[(size_t)(m0 + tid) * PRED + t] = f2b(pr);
        }
    }
}

extern "C" void kernel_launch(void* const* d_in, const int* in_sizes, int n_in,
                              void* d_out, int out_size, void* d_ws, size_t ws_size,
                              hipStream_t stream) {
    if (ws_size >= (size_t)WS_NEEDED) {
        char* ws = (char*)d_ws;
        unsigned short* Wp = (unsigned short*)ws;          // 393216 B
        float* u   = (float*)(ws + 393216);
        float* c   = (float*)(ws + 396288);
        float* bhn = (float*)(ws + 399360);
        float* wo  = (float*)(ws + 400384);
        float* b0  = (float*)(ws + 401408);
        prep_proj<<<TH, 64, 0, stream>>>(d_in[3], d_in[1], d_in[2], d_in[4], d_in[6],
                                         d_in[7], d_in[8], u, c, bhn, wo, b0);
        prep_swz<<<96, 256, 0, stream>>>(d_in[5], Wp);
        decode_swz<<<NS / 64, 1024, 0, stream>>>(d_in[0], d_in[3], Wp, u, c, bhn, wo, b0, d_out);
    } else {
        decode_all<<<NS / 64, 512, 0, stream>>>(d_in[0], d_in[1], d_in[2], d_in[3],
                                                d_in[4], d_in[5], d_in[6], d_in[7],
                                                d_in[8], d_out);
    }
}